// Round 12
// baseline (2466.659 us; speedup 1.0000x reference)
//
#include <hip/hip_runtime.h>
#include <cstdint>

// ---------------- problem constants ----------------
namespace {
constexpr int BG   = 8;
constexpr int NPG  = 16384;
constexpr int NN   = BG * NPG;     // 131072 clusters
constexpr int KK   = 6;            // knn k (with self loop)
constexpr int C0PG = 2048;
constexpr int C0N  = BG * C0PG;    // 16384 superclusters_0
constexpr int C1PG = 256;
constexpr int C1N  = BG * C1PG;    // 2048 superclusters_1
constexpr int D    = 64;
constexpr int SEG0 = C0PG / 256;   // 8 candidate segments for SC0 knn
constexpr int VS8  = 260;          // edge vbuf stride: 32 nodes x 8 slots + pad
constexpr int NMS  = 132;          // node_mm vbuf stride
}

// float -> order-preserving uint (for atomic float max; exact & deterministic)
__device__ __forceinline__ unsigned f2u_ord(float v) {
  unsigned u = __float_as_uint(v);
  return (u & 0x80000000u) ? ~u : (u | 0x80000000u);
}

__global__ void k_init_u32(unsigned* __restrict__ p, unsigned v, int n) {
  int i = blockIdx.x * blockDim.x + threadIdx.x;
  if (i < n) p[i] = v;
}

__global__ void k_seg_max_i32(const int* __restrict__ vals, const int* __restrict__ seg,
                              int* __restrict__ out, int n) {
  int i = blockIdx.x * blockDim.x + threadIdx.x;
  if (i < n) atomicMax(&out[seg[i]], vals[i]);
}

template <int NB>
__global__ __launch_bounds__(256) void k_seg_max_small(
    const int* __restrict__ vals, const int* __restrict__ seg,
    int* __restrict__ out, int n) {
  __shared__ int lmx[NB];
  int t = threadIdx.x;
  if (t < NB) lmx[t] = (int)0x80000000;
  __syncthreads();
  for (int i = blockIdx.x * 256 + t; i < n; i += gridDim.x * 256)
    atomicMax(&lmx[seg[i]], vals[i]);
  __syncthreads();
  if (t < NB) atomicMax(&out[t], lmx[t]);
}

__global__ void k_cumsum_off(const int* __restrict__ mx, int* __restrict__ off, int nb) {
  if (threadIdx.x == 0 && blockIdx.x == 0) {
    int a = 0; off[0] = 0;
    for (int b = 0; b < nb; ++b) { a += mx[b] + 1; off[b + 1] = a; }
  }
}

__global__ void k_gen_cl(const int* __restrict__ ids, const int* __restrict__ bt,
                         const int* __restrict__ off, int* __restrict__ cl, int n) {
  int i = blockIdx.x * blockDim.x + threadIdx.x;
  if (i < n) cl[i] = ids[i] + off[bt[i]];
}

__global__ void k_pool_f32(const float* __restrict__ h, const int* __restrict__ cl,
                           unsigned* __restrict__ outu, int total) {
  int i = blockIdx.x * blockDim.x + threadIdx.x;
  if (i < total) atomicMax(&outu[(size_t)cl[i >> 6] * D + (i & 63)], f2u_ord(h[i]));
}

__global__ void k_decode_f32(unsigned* __restrict__ p, int n) {
  int i = blockIdx.x * blockDim.x + threadIdx.x;
  if (i < n) { unsigned u = p[i]; p[i] = (u & 0x80000000u) ? (u ^ 0x80000000u) : ~u; }
}

// legacy single-pass knn (SC1 only, npg=256). NO fp contraction (selection-exact).
__global__ __launch_bounds__(256) void k_knn(const float* __restrict__ pos, int npg,
                                             int* __restrict__ srcOut) {
  #pragma clang fp contract(off)
  __shared__ float px[2048], py[2048], sq[2048];
  int t = threadIdx.x;
  int nglob = blockIdx.x * 256 + t;
  int graph = nglob / npg;
  int base = graph * npg;
  for (int i = t; i < npg; i += 256) {
    float xx = pos[2 * (base + i)];
    float yy = pos[2 * (base + i) + 1];
    px[i] = xx; py[i] = yy;
    float a = xx * xx; float b = yy * yy;
    sq[i] = a + b;
  }
  __syncthreads();
  int i = nglob - base;
  float xi = px[i], yi = py[i], sqi = sq[i];
  float bd[KK]; int bi[KK];
  #pragma unroll
  for (int q = 0; q < KK; ++q) { bd[q] = 3.4e38f; bi[q] = 0; }
  for (int j = 0; j < npg; ++j) {
    float t1 = xi * px[j];
    float t2 = yi * py[j];
    float dot = t1 + t2;
    float d2 = (sqi + sq[j]) - 2.0f * dot;
    if (d2 < bd[KK - 1]) {
      bd[KK - 1] = d2; bi[KK - 1] = j;
      #pragma unroll
      for (int q = KK - 1; q > 0; --q) {
        if (bd[q] < bd[q - 1]) {
          float td = bd[q]; bd[q] = bd[q - 1]; bd[q - 1] = td;
          int ti = bi[q]; bi[q] = bi[q - 1]; bi[q - 1] = ti;
        }
      }
    }
  }
  #pragma unroll
  for (int q = 0; q < KK; ++q) srcOut[(size_t)nglob * KK + q] = base + bi[q];
}

// partitioned knn pass 1 (SC0): block = query-tile(256) x candidate-segment(256)
__global__ __launch_bounds__(256) void k_knn_part(const float* __restrict__ pos, int npg,
                                                  int nseg,
                                                  float* __restrict__ outD,
                                                  int* __restrict__ outI) {
  #pragma clang fp contract(off)
  __shared__ float cx[256], cy[256], cs[256];
  int t = threadIdx.x;
  int qt = blockIdx.x / nseg;
  int s  = blockIdx.x % nseg;
  int qlo = qt * 256;
  int graph = qlo / npg;
  int base = graph * npg;
  int cbase = base + s * 256;
  {
    float xx = pos[2 * (cbase + t)];
    float yy = pos[2 * (cbase + t) + 1];
    cx[t] = xx; cy[t] = yy;
    float a = xx * xx; float b = yy * yy;
    cs[t] = a + b;
  }
  __syncthreads();
  int q = qlo + t;
  float xi = pos[2 * q], yi = pos[2 * q + 1];
  float qa = xi * xi; float qb = yi * yi;
  float sqi = qa + qb;
  float bd[KK]; int bi[KK];
  #pragma unroll
  for (int u = 0; u < KK; ++u) { bd[u] = 3.4e38f; bi[u] = 0; }
  for (int j = 0; j < 256; ++j) {
    float t1 = xi * cx[j];
    float t2 = yi * cy[j];
    float dot = t1 + t2;
    float d2 = (sqi + cs[j]) - 2.0f * dot;
    if (d2 < bd[KK - 1]) {
      bd[KK - 1] = d2; bi[KK - 1] = cbase + j;
      #pragma unroll
      for (int u = KK - 1; u > 0; --u) {
        if (bd[u] < bd[u - 1]) {
          float td = bd[u]; bd[u] = bd[u - 1]; bd[u - 1] = td;
          int ti = bi[u]; bi[u] = bi[u - 1]; bi[u - 1] = ti;
        }
      }
    }
  }
  size_t ob = (size_t)q * (nseg * KK) + (size_t)s * KK;
  #pragma unroll
  for (int u = 0; u < KK; ++u) { outD[ob + u] = bd[u]; outI[ob + u] = bi[u]; }
}

__global__ void k_knn_merge(const float* __restrict__ inD, const int* __restrict__ inI,
                            int nseg, int* __restrict__ srcOut, int nq) {
  int q = blockIdx.x * blockDim.x + threadIdx.x;
  if (q >= nq) return;
  float bd[KK]; int bi[KK];
  #pragma unroll
  for (int u = 0; u < KK; ++u) { bd[u] = 3.4e38f; bi[u] = 0x7fffffff; }
  size_t ib = (size_t)q * (nseg * KK);
  for (int e = 0; e < nseg * KK; ++e) {
    float d = inD[ib + e]; int ix = inI[ib + e];
    bool lt = (d < bd[KK - 1]) || (d == bd[KK - 1] && ix < bi[KK - 1]);
    if (lt) {
      bd[KK - 1] = d; bi[KK - 1] = ix;
      #pragma unroll
      for (int u = KK - 1; u > 0; --u) {
        bool sw = (bd[u] < bd[u - 1]) || (bd[u] == bd[u - 1] && bi[u] < bi[u - 1]);
        if (sw) {
          float td = bd[u]; bd[u] = bd[u - 1]; bd[u - 1] = td;
          int ti = bi[u]; bi[u] = bi[u - 1]; bi[u - 1] = ti;
        }
      }
    }
  }
  #pragma unroll
  for (int u = 0; u < KK; ++u) srcOut[(size_t)q * KK + u] = bi[u];
}

// node matmuls xv/as/ad = h @ {Wlin,Wsrc,Wdst}. R12: W read from GLOBAL
// (L1/L2-resident, VMEM pipe w/ vmcnt pipelining) -> DS per kk drops 3->1,
// wbuf + its stagings + 4 barriers deleted. DS pipe was the bottleneck.
__global__ void __launch_bounds__(256)
__attribute__((amdgpu_waves_per_eu(4, 4)))
k_node_mm(const float* __restrict__ hin,
    const float* __restrict__ Wl, const float* __restrict__ Ws, const float* __restrict__ Wd,
    float* __restrict__ xv, float* __restrict__ as_, float* __restrict__ ad_) {
  __shared__ float vbuf[32 * NMS];
  int t = threadIdx.x;
  size_t nb = (size_t)blockIdx.x * 128;
  int ng = t >> 3, cb = t & 7, c0 = cb * 8;
  const float* Wm[3] = {Wl, Ws, Wd};
  float* Om[3] = {xv, as_, ad_};
  const float4* h4 = (const float4*)hin;
  float acc[3][32];
  #pragma unroll
  for (int m = 0; m < 3; ++m)
    #pragma unroll
    for (int i = 0; i < 32; ++i) acc[m][i] = 0.0f;
  for (int kh = 0; kh < 2; ++kh) {
    if (kh) __syncthreads();            // vbuf consumers of previous half done
    #pragma unroll
    for (int r = 0; r < 4; ++r) {
      int flat = r * 256 + t;
      int n = flat >> 3, kq = flat & 7;
      float4 hv = h4[(nb + n) * 16 + kh * 8 + kq];
      vbuf[(kq * 4 + 0) * NMS + n] = hv.x;
      vbuf[(kq * 4 + 1) * NMS + n] = hv.y;
      vbuf[(kq * 4 + 2) * NMS + n] = hv.z;
      vbuf[(kq * 4 + 3) * NMS + n] = hv.w;
    }
    __syncthreads();
    #pragma unroll
    for (int m = 0; m < 3; ++m) {
      const float4* Wg = (const float4*)(Wm[m] + (size_t)kh * 2048);
      #pragma clang loop unroll_count(2)
      for (int kk = 0; kk < 32; ++kk) {
        float4 v4 = *(const float4*)&vbuf[kk * NMS + 4 * ng];
        float4 w0 = Wg[kk * 16 + 2 * cb];
        float4 w1 = Wg[kk * 16 + 2 * cb + 1];
        float vv[4] = {v4.x, v4.y, v4.z, v4.w};
        float wv[8] = {w0.x, w0.y, w0.z, w0.w, w1.x, w1.y, w1.z, w1.w};
        #pragma unroll
        for (int ni = 0; ni < 4; ++ni)
          #pragma unroll
          for (int c = 0; c < 8; ++c)
            acc[m][ni * 8 + c] = fmaf(vv[ni], wv[c], acc[m][ni * 8 + c]);
      }
    }
  }
  #pragma unroll
  for (int m = 0; m < 3; ++m) {
    float* O = Om[m];
    #pragma unroll
    for (int ni = 0; ni < 4; ++ni) {
      *(float4*)(O + (nb + 4 * ng + ni) * 64 + c0) =
          make_float4(acc[m][ni * 8 + 0], acc[m][ni * 8 + 1],
                      acc[m][ni * 8 + 2], acc[m][ni * 8 + 3]);
      *(float4*)(O + (nb + 4 * ng + ni) * 64 + c0 + 4) =
          make_float4(acc[m][ni * 8 + 4], acc[m][ni * 8 + 5],
                      acc[m][ni * 8 + 6], acc[m][ni * 8 + 7]);
    }
  }
}

// Fused edge MLPs + softmax-aggregate. R12: W from GLOBAL (VMEM pipe) — wbuf,
// wreg prefetch, and W stagings deleted (DS was 95%-saturated: 890 DS instr/wave
// x 12cyc x 64 waves/CU = 285us = the measured plateau). vbuf rows ROTATED
// (physical row = (k+ng)&31): read banks (4k+12ng)&31 distinct over ng ->
// kills R11's 11M 2-way conflicts; staging writes spread to 8 quads.
// Arithmetic order identical -> bit-exact.
__global__ void __launch_bounds__(256)
__attribute__((amdgpu_waves_per_eu(3, 3)))
k_edge_fused(
    const float* __restrict__ pos, const int* __restrict__ srcA,
    const float* __restrict__ as_, const float* __restrict__ ad_,
    const float* __restrict__ xv,
    const float* __restrict__ pW1, const float* __restrict__ pB1,
    const float* __restrict__ pW2, const float* __restrict__ pB2,
    const float* __restrict__ aW1, const float* __restrict__ aB1,
    const float* __restrict__ aW2, const float* __restrict__ aB2,
    float* __restrict__ hout) {
  __shared__ float vbuf[32 * VS8];    // 33.3 KB: [rotated k-row][8*node+edge]
  __shared__ float sbuf[192];         // pW1 | pB1
  __shared__ float pdxs[192], pdys[192];
  __shared__ int   srcb[192];
  int t = threadIdx.x;
  int nb = blockIdx.x * 32;
  int ng = t >> 3;                    // node-in-block 0..31
  int cb = t & 7;
  int cl = 4 * cb;                    // low channel quad (half 0)
  int ch = 32 + 4 * cb;               // high channel quad (half 1)
  int node = nb + ng;
  int ecol = 8 * ng;                  // this thread's edge-column base

  // ---- prologue ----
  int nd = t / 6;                     // staging node for edge-thread t (t<192)
  int mycol = 8 * nd + (t % 6);
  if (t < 192) {
    int s = srcA[(size_t)nb * KK + t];
    srcb[t] = s;
    float2 pd = *(const float2*)(pos + 2 * (size_t)(nb + nd));
    float2 ps = *(const float2*)(pos + 2 * (size_t)s);
    pdxs[t] = pd.x - ps.x;
    pdys[t] = pd.y - ps.y;
    sbuf[t] = (t < 128) ? pW1[t] : pB1[t - 128];
  }
  __syncthreads();

  // ---- phase 1: delta = relu(relu(pd@pW1+pB1)@pW2 + pB2) ----
  float d[48];
  {
    float4 b0 = *(const float4*)(pB2 + cl);
    float4 b1 = *(const float4*)(pB2 + ch);
    #pragma unroll
    for (int j = 0; j < 6; ++j) {
      d[j * 8 + 0] = b0.x; d[j * 8 + 1] = b0.y; d[j * 8 + 2] = b0.z; d[j * 8 + 3] = b0.w;
      d[j * 8 + 4] = b1.x; d[j * 8 + 5] = b1.y; d[j * 8 + 6] = b1.z; d[j * 8 + 7] = b1.w;
    }
  }
  #pragma unroll
  for (int h = 0; h < 2; ++h) {
    if (t < 192) {
      float px = pdxs[t], py = pdys[t];
      #pragma clang loop unroll_count(4)
      for (int kk = 0; kk < 32; ++kk) {
        int k = h * 32 + kk;
        float p0 = px * sbuf[k];
        float p1 = py * sbuf[64 + k];
        float ph = fmaxf((p0 + p1) + sbuf[128 + k], 0.0f);
        vbuf[((kk + nd) & 31) * VS8 + mycol] = ph;
      }
    }
    __syncthreads();
    {
      const float4* Wg = (const float4*)(pW2 + (size_t)h * 2048);
      #pragma clang loop unroll_count(2)
      for (int kk = 0; kk < 32; ++kk) {
        int rrow = (kk + ng) & 31;
        float4 va = *(const float4*)&vbuf[rrow * VS8 + ecol];
        float4 vb = *(const float4*)&vbuf[rrow * VS8 + ecol + 4];
        float4 w0 = Wg[kk * 16 + cb];
        float4 w1 = Wg[kk * 16 + 8 + cb];
        float vv[6] = {va.x, va.y, va.z, va.w, vb.x, vb.y};
        float wv[8] = {w0.x, w0.y, w0.z, w0.w, w1.x, w1.y, w1.z, w1.w};
        #pragma unroll
        for (int j = 0; j < 6; ++j)
          #pragma unroll
          for (int c = 0; c < 8; ++c)
            d[j * 8 + c] = fmaf(vv[j], wv[c], d[j * 8 + c]);
      }
    }
    __syncthreads();
  }
  #pragma unroll
  for (int i = 0; i < 48; ++i) d[i] = fmaxf(d[i], 0.0f);

  // ---- phase 2: r = relu(v @ aW1 + aB1), v = (ad-as)+delta ----
  float r[48];
  {
    float4 b0 = *(const float4*)(aB1 + cl);
    float4 b1 = *(const float4*)(aB1 + ch);
    #pragma unroll
    for (int j = 0; j < 6; ++j) {
      r[j * 8 + 0] = b0.x; r[j * 8 + 1] = b0.y; r[j * 8 + 2] = b0.z; r[j * 8 + 3] = b0.w;
      r[j * 8 + 4] = b1.x; r[j * 8 + 5] = b1.y; r[j * 8 + 6] = b1.z; r[j * 8 + 7] = b1.w;
    }
  }
  #pragma unroll
  for (int h = 0; h < 2; ++h) {
    {
      int cbase = h ? ch : cl;
      float4 av = *(const float4*)(ad_ + (size_t)node * 64 + cbase);
      float vtmp[6][4];
      #pragma unroll
      for (int j = 0; j < 6; ++j) {
        int s = srcb[6 * ng + j];
        float4 sv = *(const float4*)(as_ + (size_t)s * 64 + cbase);
        vtmp[j][0] = (av.x - sv.x) + d[j * 8 + 4 * h + 0];
        vtmp[j][1] = (av.y - sv.y) + d[j * 8 + 4 * h + 1];
        vtmp[j][2] = (av.z - sv.z) + d[j * 8 + 4 * h + 2];
        vtmp[j][3] = (av.w - sv.w) + d[j * 8 + 4 * h + 3];
      }
      #pragma unroll
      for (int cj = 0; cj < 4; ++cj) {
        int prow = (4 * cb + cj + ng) & 31;
        *(float4*)&vbuf[prow * VS8 + ecol] =
            make_float4(vtmp[0][cj], vtmp[1][cj], vtmp[2][cj], vtmp[3][cj]);
        *(float2*)&vbuf[prow * VS8 + ecol + 4] = make_float2(vtmp[4][cj], vtmp[5][cj]);
      }
    }
    __syncthreads();
    {
      const float4* Wg = (const float4*)(aW1 + (size_t)h * 2048);
      #pragma clang loop unroll_count(2)
      for (int kk = 0; kk < 32; ++kk) {
        int rrow = (kk + ng) & 31;
        float4 va = *(const float4*)&vbuf[rrow * VS8 + ecol];
        float4 vb = *(const float4*)&vbuf[rrow * VS8 + ecol + 4];
        float4 w0 = Wg[kk * 16 + cb];
        float4 w1 = Wg[kk * 16 + 8 + cb];
        float vv[6] = {va.x, va.y, va.z, va.w, vb.x, vb.y};
        float wv[8] = {w0.x, w0.y, w0.z, w0.w, w1.x, w1.y, w1.z, w1.w};
        #pragma unroll
        for (int j = 0; j < 6; ++j)
          #pragma unroll
          for (int c = 0; c < 8; ++c)
            r[j * 8 + c] = fmaf(vv[j], wv[c], r[j * 8 + c]);
      }
    }
    __syncthreads();
  }
  #pragma unroll
  for (int i = 0; i < 48; ++i) r[i] = fmaxf(r[i], 0.0f);

  // ---- phase 3: a = relu(r @ aW2 + aB2) ----
  float a[48];
  {
    float4 b0 = *(const float4*)(aB2 + cl);
    float4 b1 = *(const float4*)(aB2 + ch);
    #pragma unroll
    for (int j = 0; j < 6; ++j) {
      a[j * 8 + 0] = b0.x; a[j * 8 + 1] = b0.y; a[j * 8 + 2] = b0.z; a[j * 8 + 3] = b0.w;
      a[j * 8 + 4] = b1.x; a[j * 8 + 5] = b1.y; a[j * 8 + 6] = b1.z; a[j * 8 + 7] = b1.w;
    }
  }
  #pragma unroll
  for (int h = 0; h < 2; ++h) {
    #pragma unroll
    for (int cj = 0; cj < 4; ++cj) {
      int prow = (4 * cb + cj + ng) & 31;
      *(float4*)&vbuf[prow * VS8 + ecol] =
          make_float4(r[0 * 8 + 4 * h + cj], r[1 * 8 + 4 * h + cj],
                      r[2 * 8 + 4 * h + cj], r[3 * 8 + 4 * h + cj]);
      *(float2*)&vbuf[prow * VS8 + ecol + 4] =
          make_float2(r[4 * 8 + 4 * h + cj], r[5 * 8 + 4 * h + cj]);
    }
    __syncthreads();
    {
      const float4* Wg = (const float4*)(aW2 + (size_t)h * 2048);
      #pragma clang loop unroll_count(2)
      for (int kk = 0; kk < 32; ++kk) {
        int rrow = (kk + ng) & 31;
        float4 va = *(const float4*)&vbuf[rrow * VS8 + ecol];
        float4 vb = *(const float4*)&vbuf[rrow * VS8 + ecol + 4];
        float4 w0 = Wg[kk * 16 + cb];
        float4 w1 = Wg[kk * 16 + 8 + cb];
        float vv[6] = {va.x, va.y, va.z, va.w, vb.x, vb.y};
        float wv[8] = {w0.x, w0.y, w0.z, w0.w, w1.x, w1.y, w1.z, w1.w};
        #pragma unroll
        for (int j = 0; j < 6; ++j)
          #pragma unroll
          for (int c = 0; c < 8; ++c)
            a[j * 8 + c] = fmaf(vv[j], wv[c], a[j * 8 + c]);
      }
    }
    __syncthreads();
  }
  #pragma unroll
  for (int i = 0; i < 48; ++i) a[i] = fmaxf(a[i], 0.0f);

  // ---- phase 4: thread-local softmax + max-aggregate (exact reference order) ----
  float m8[8], ss[8], out[8];
  #pragma unroll
  for (int c = 0; c < 8; ++c) m8[c] = a[c];
  #pragma unroll
  for (int j = 1; j < 6; ++j)
    #pragma unroll
    for (int c = 0; c < 8; ++c) m8[c] = fmaxf(m8[c], a[j * 8 + c]);
  #pragma unroll
  for (int c = 0; c < 8; ++c) ss[c] = 0.0f;
  #pragma unroll
  for (int j = 0; j < 6; ++j)
    #pragma unroll
    for (int c = 0; c < 8; ++c) ss[c] += expf(a[j * 8 + c] - m8[c]);
  #pragma unroll
  for (int j = 0; j < 6; ++j) {
    int s = srcb[6 * ng + j];
    float4 x0 = *(const float4*)(xv + (size_t)s * 64 + cl);
    float4 x1 = *(const float4*)(xv + (size_t)s * 64 + ch);
    float xa[8] = {x0.x, x0.y, x0.z, x0.w, x1.x, x1.y, x1.z, x1.w};
    #pragma unroll
    for (int c = 0; c < 8; ++c) {
      float ej = expf(a[j * 8 + c] - m8[c]);
      float alpha = ej / ss[c];
      float val = alpha * (xa[c] + d[j * 8 + c]);
      out[c] = (j == 0) ? val : fmaxf(out[c], val);
    }
  }
  *(float4*)(hout + (size_t)node * 64 + cl) = make_float4(out[0], out[1], out[2], out[3]);
  *(float4*)(hout + (size_t)node * 64 + ch) = make_float4(out[4], out[5], out[6], out[7]);
}

__global__ void k_head(const float* __restrict__ g, const float* __restrict__ hw,
                       const float* __restrict__ hb, float* __restrict__ out) {
  int t = threadIdx.x;
  if (t >= BG * 2) return;
  int b = t >> 1, o = t & 1;
  float acc = 0.0f;
  for (int k = 0; k < D; ++k) acc = fmaf(g[b * D + k], hw[k * 2 + o], acc);
  out[b * 2 + o] = acc + hb[o];
}

extern "C" void kernel_launch(void* const* d_in, const int* in_sizes, int n_in,
                              void* d_out, int out_size, void* d_ws, size_t ws_size,
                              hipStream_t stream) {
  (void)in_sizes; (void)n_in; (void)out_size; (void)ws_size;
  const float* x      = (const float*)d_in[0];
  const float* pos_c  = (const float*)d_in[1];
  const int*   src_c  = (const int*)d_in[2];
  const int*   batch  = (const int*)d_in[4];
  const int*   sc_id0 = (const int*)d_in[5];
  const float* pos_s0 = (const float*)d_in[6];
  const int*   sc_id1 = (const int*)d_in[7];
  const float* pos_s1 = (const float*)d_in[8];
  const float* Wlin = (const float*)d_in[9];
  const float* Wsrc = (const float*)d_in[10];
  const float* Wdst = (const float*)d_in[11];
  const float* pW1  = (const float*)d_in[12];
  const float* pB1  = (const float*)d_in[13];
  const float* pW2  = (const float*)d_in[14];
  const float* pB2  = (const float*)d_in[15];
  const float* aW1  = (const float*)d_in[16];
  const float* aB1  = (const float*)d_in[17];
  const float* aW2  = (const float*)d_in[18];
  const float* aB2  = (const float*)d_in[19];
  const float* hw   = (const float*)d_in[20];
  const float* hb   = (const float*)d_in[21];
  float* outp = (float*)d_out;

  char* ws = (char*)d_ws;
  size_t off = 0;
  auto alloc = [&](size_t bytes) -> void* {
    void* p = ws + off; off = (off + bytes + 255) & ~(size_t)255; return p;
  };
  float* h   = (float*)alloc((size_t)NN * D * 4);
  float* xv  = (float*)alloc((size_t)NN * D * 4);
  float* as_ = (float*)alloc((size_t)NN * D * 4);
  float* ad_ = (float*)alloc((size_t)NN * D * 4);
  float* h0  = (float*)alloc((size_t)C0N * D * 4);
  float* h1  = (float*)alloc((size_t)C1N * D * 4);
  float* g   = (float*)alloc((size_t)BG * D * 4);
  int* cl0   = (int*)alloc((size_t)NN * 4);
  int* cl1   = (int*)alloc((size_t)C0N * 4);
  int* b0    = (int*)alloc((size_t)C0N * 4);
  int* b1    = (int*)alloc((size_t)C1N * 4);
  int* src0  = (int*)alloc((size_t)C0N * KK * 4);
  int* src1  = (int*)alloc((size_t)C1N * KK * 4);
  float* kd  = (float*)alloc((size_t)C0N * SEG0 * KK * 4);
  int*   ki  = (int*)alloc((size_t)C0N * SEG0 * KK * 4);
  int* mx    = (int*)alloc(256);
  int* offb  = (int*)alloc(256);

  auto ptconv = [&](int n, const float* pos, const int* srcA,
                    const float* hin, float* hout, int l) {
    k_node_mm<<<n / 128, 256, 0, stream>>>(hin,
        Wlin + (size_t)l * 4096, Wsrc + (size_t)l * 4096, Wdst + (size_t)l * 4096,
        xv, as_, ad_);
    k_edge_fused<<<n / 32, 256, 0, stream>>>(pos, srcA, as_, ad_, xv,
        pW1 + (size_t)l * 128, pB1 + (size_t)l * 64,
        pW2 + (size_t)l * 4096, pB2 + (size_t)l * 64,
        aW1 + (size_t)l * 4096, aB1 + (size_t)l * 64,
        aW2 + (size_t)l * 4096, aB2 + (size_t)l * 64,
        hout);
  };

  // ---- structure precompute (gen_cluster, batches, knn graphs) ----
  k_init_u32<<<1, 64, 0, stream>>>((unsigned*)mx, 0x80000000u, BG);
  k_seg_max_small<BG><<<64, 256, 0, stream>>>(sc_id0, batch, mx, NN);
  k_cumsum_off<<<1, 1, 0, stream>>>(mx, offb, BG);
  k_gen_cl<<<NN / 256, 256, 0, stream>>>(sc_id0, batch, offb, cl0, NN);
  k_init_u32<<<(C0N + 255) / 256, 256, 0, stream>>>((unsigned*)b0, 0x80000000u, C0N);
  k_seg_max_i32<<<NN / 256, 256, 0, stream>>>(batch, cl0, b0, NN);
  k_knn_part<<<(C0N / 256) * SEG0, 256, 0, stream>>>(pos_s0, C0PG, SEG0, kd, ki);
  k_knn_merge<<<C0N / 256, 256, 0, stream>>>(kd, ki, SEG0, src0, C0N);
  k_init_u32<<<1, 64, 0, stream>>>((unsigned*)mx, 0x80000000u, BG);
  k_seg_max_small<BG><<<64, 256, 0, stream>>>(sc_id1, b0, mx, C0N);
  k_cumsum_off<<<1, 1, 0, stream>>>(mx, offb, BG);
  k_gen_cl<<<C0N / 256, 256, 0, stream>>>(sc_id1, b0, offb, cl1, C0N);
  k_init_u32<<<(C1N + 255) / 256, 256, 0, stream>>>((unsigned*)b1, 0x80000000u, C1N);
  k_seg_max_i32<<<C0N / 256, 256, 0, stream>>>(b0, cl1, b1, C0N);
  k_knn<<<C1N / 256, 256, 0, stream>>>(pos_s1, C1PG, src1);

  // ---- cluster level (4 layers) ----
  ptconv(NN, pos_c, src_c, x, h, 0);
  for (int l = 1; l < 4; ++l) ptconv(NN, pos_c, src_c, h, h, l);
  // pool -> h0
  k_init_u32<<<C0N * D / 256, 256, 0, stream>>>((unsigned*)h0, 0x007fffffu, C0N * D);
  k_pool_f32<<<NN * D / 256, 256, 0, stream>>>(h, cl0, (unsigned*)h0, NN * D);
  k_decode_f32<<<C0N * D / 256, 256, 0, stream>>>((unsigned*)h0, C0N * D);
  // ---- SC0 level (3 layers) ----
  for (int l = 4; l < 7; ++l) ptconv(C0N, pos_s0, src0, h0, h0, l);
  // pool -> h1
  k_init_u32<<<C1N * D / 256, 256, 0, stream>>>((unsigned*)h1, 0x007fffffu, C1N * D);
  k_pool_f32<<<C0N * D / 256, 256, 0, stream>>>(h0, cl1, (unsigned*)h1, C0N * D);
  k_decode_f32<<<C1N * D / 256, 256, 0, stream>>>((unsigned*)h1, C1N * D);
  // ---- SC1 level (3 layers) ----
  for (int l = 7; l < 10; ++l) ptconv(C1N, pos_s1, src1, h1, h1, l);
  // ---- global max pool + head ----
  k_init_u32<<<(BG * D + 255) / 256, 256, 0, stream>>>((unsigned*)g, 0x007fffffu, BG * D);
  k_pool_f32<<<C1N * D / 256, 256, 0, stream>>>(h1, b1, (unsigned*)g, C1N * D);
  k_decode_f32<<<(BG * D + 255) / 256, 256, 0, stream>>>((unsigned*)g, BG * D);
  k_head<<<1, 64, 0, stream>>>(g, hw, hb, outp);
}

// Round 13
// 1866.954 us; speedup vs baseline: 1.3212x; 1.3212x over previous
//
#include <hip/hip_runtime.h>
#include <cstdint>

// ---------------- problem constants ----------------
namespace {
constexpr int BG   = 8;
constexpr int NPG  = 16384;
constexpr int NN   = BG * NPG;     // 131072 clusters
constexpr int KK   = 6;            // knn k (with self loop)
constexpr int C0PG = 2048;
constexpr int C0N  = BG * C0PG;    // 16384 superclusters_0
constexpr int C1PG = 256;
constexpr int C1N  = BG * C1PG;    // 2048 superclusters_1
constexpr int D    = 64;
constexpr int SEG0 = C0PG / 256;   // 8 candidate segments for SC0 knn
constexpr int VS   = 198;          // edge vbuf stride (192 edges + pad, even)
constexpr int NMS  = 132;          // node_mm vbuf stride
}

// float -> order-preserving uint (for atomic float max; exact & deterministic)
__device__ __forceinline__ unsigned f2u_ord(float v) {
  unsigned u = __float_as_uint(v);
  return (u & 0x80000000u) ? ~u : (u | 0x80000000u);
}

__global__ void k_init_u32(unsigned* __restrict__ p, unsigned v, int n) {
  int i = blockIdx.x * blockDim.x + threadIdx.x;
  if (i < n) p[i] = v;
}

__global__ void k_seg_max_i32(const int* __restrict__ vals, const int* __restrict__ seg,
                              int* __restrict__ out, int n) {
  int i = blockIdx.x * blockDim.x + threadIdx.x;
  if (i < n) atomicMax(&out[seg[i]], vals[i]);
}

template <int NB>
__global__ __launch_bounds__(256) void k_seg_max_small(
    const int* __restrict__ vals, const int* __restrict__ seg,
    int* __restrict__ out, int n) {
  __shared__ int lmx[NB];
  int t = threadIdx.x;
  if (t < NB) lmx[t] = (int)0x80000000;
  __syncthreads();
  for (int i = blockIdx.x * 256 + t; i < n; i += gridDim.x * 256)
    atomicMax(&lmx[seg[i]], vals[i]);
  __syncthreads();
  if (t < NB) atomicMax(&out[t], lmx[t]);
}

__global__ void k_cumsum_off(const int* __restrict__ mx, int* __restrict__ off, int nb) {
  if (threadIdx.x == 0 && blockIdx.x == 0) {
    int a = 0; off[0] = 0;
    for (int b = 0; b < nb; ++b) { a += mx[b] + 1; off[b + 1] = a; }
  }
}

__global__ void k_gen_cl(const int* __restrict__ ids, const int* __restrict__ bt,
                         const int* __restrict__ off, int* __restrict__ cl, int n) {
  int i = blockIdx.x * blockDim.x + threadIdx.x;
  if (i < n) cl[i] = ids[i] + off[bt[i]];
}

__global__ void k_pool_f32(const float* __restrict__ h, const int* __restrict__ cl,
                           unsigned* __restrict__ outu, int total) {
  int i = blockIdx.x * blockDim.x + threadIdx.x;
  if (i < total) atomicMax(&outu[(size_t)cl[i >> 6] * D + (i & 63)], f2u_ord(h[i]));
}

__global__ void k_decode_f32(unsigned* __restrict__ p, int n) {
  int i = blockIdx.x * blockDim.x + threadIdx.x;
  if (i < n) { unsigned u = p[i]; p[i] = (u & 0x80000000u) ? (u ^ 0x80000000u) : ~u; }
}

// legacy single-pass knn (SC1 only, npg=256). NO fp contraction (selection-exact).
__global__ __launch_bounds__(256) void k_knn(const float* __restrict__ pos, int npg,
                                             int* __restrict__ srcOut) {
  #pragma clang fp contract(off)
  __shared__ float px[2048], py[2048], sq[2048];
  int t = threadIdx.x;
  int nglob = blockIdx.x * 256 + t;
  int graph = nglob / npg;
  int base = graph * npg;
  for (int i = t; i < npg; i += 256) {
    float xx = pos[2 * (base + i)];
    float yy = pos[2 * (base + i) + 1];
    px[i] = xx; py[i] = yy;
    float a = xx * xx; float b = yy * yy;
    sq[i] = a + b;
  }
  __syncthreads();
  int i = nglob - base;
  float xi = px[i], yi = py[i], sqi = sq[i];
  float bd[KK]; int bi[KK];
  #pragma unroll
  for (int q = 0; q < KK; ++q) { bd[q] = 3.4e38f; bi[q] = 0; }
  for (int j = 0; j < npg; ++j) {
    float t1 = xi * px[j];
    float t2 = yi * py[j];
    float dot = t1 + t2;
    float d2 = (sqi + sq[j]) - 2.0f * dot;
    if (d2 < bd[KK - 1]) {
      bd[KK - 1] = d2; bi[KK - 1] = j;
      #pragma unroll
      for (int q = KK - 1; q > 0; --q) {
        if (bd[q] < bd[q - 1]) {
          float td = bd[q]; bd[q] = bd[q - 1]; bd[q - 1] = td;
          int ti = bi[q]; bi[q] = bi[q - 1]; bi[q - 1] = ti;
        }
      }
    }
  }
  #pragma unroll
  for (int q = 0; q < KK; ++q) srcOut[(size_t)nglob * KK + q] = base + bi[q];
}

// partitioned knn pass 1 (SC0): block = query-tile(256) x candidate-segment(256)
__global__ __launch_bounds__(256) void k_knn_part(const float* __restrict__ pos, int npg,
                                                  int nseg,
                                                  float* __restrict__ outD,
                                                  int* __restrict__ outI) {
  #pragma clang fp contract(off)
  __shared__ float cx[256], cy[256], cs[256];
  int t = threadIdx.x;
  int qt = blockIdx.x / nseg;
  int s  = blockIdx.x % nseg;
  int qlo = qt * 256;
  int graph = qlo / npg;
  int base = graph * npg;
  int cbase = base + s * 256;
  {
    float xx = pos[2 * (cbase + t)];
    float yy = pos[2 * (cbase + t) + 1];
    cx[t] = xx; cy[t] = yy;
    float a = xx * xx; float b = yy * yy;
    cs[t] = a + b;
  }
  __syncthreads();
  int q = qlo + t;
  float xi = pos[2 * q], yi = pos[2 * q + 1];
  float qa = xi * xi; float qb = yi * yi;
  float sqi = qa + qb;
  float bd[KK]; int bi[KK];
  #pragma unroll
  for (int u = 0; u < KK; ++u) { bd[u] = 3.4e38f; bi[u] = 0; }
  for (int j = 0; j < 256; ++j) {
    float t1 = xi * cx[j];
    float t2 = yi * cy[j];
    float dot = t1 + t2;
    float d2 = (sqi + cs[j]) - 2.0f * dot;
    if (d2 < bd[KK - 1]) {
      bd[KK - 1] = d2; bi[KK - 1] = cbase + j;
      #pragma unroll
      for (int u = KK - 1; u > 0; --u) {
        if (bd[u] < bd[u - 1]) {
          float td = bd[u]; bd[u] = bd[u - 1]; bd[u - 1] = td;
          int ti = bi[u]; bi[u] = bi[u - 1]; bi[u - 1] = ti;
        }
      }
    }
  }
  size_t ob = (size_t)q * (nseg * KK) + (size_t)s * KK;
  #pragma unroll
  for (int u = 0; u < KK; ++u) { outD[ob + u] = bd[u]; outI[ob + u] = bi[u]; }
}

__global__ void k_knn_merge(const float* __restrict__ inD, const int* __restrict__ inI,
                            int nseg, int* __restrict__ srcOut, int nq) {
  int q = blockIdx.x * blockDim.x + threadIdx.x;
  if (q >= nq) return;
  float bd[KK]; int bi[KK];
  #pragma unroll
  for (int u = 0; u < KK; ++u) { bd[u] = 3.4e38f; bi[u] = 0x7fffffff; }
  size_t ib = (size_t)q * (nseg * KK);
  for (int e = 0; e < nseg * KK; ++e) {
    float d = inD[ib + e]; int ix = inI[ib + e];
    bool lt = (d < bd[KK - 1]) || (d == bd[KK - 1] && ix < bi[KK - 1]);
    if (lt) {
      bd[KK - 1] = d; bi[KK - 1] = ix;
      #pragma unroll
      for (int u = KK - 1; u > 0; --u) {
        bool sw = (bd[u] < bd[u - 1]) || (bd[u] == bd[u - 1] && bi[u] < bi[u - 1]);
        if (sw) {
          float td = bd[u]; bd[u] = bd[u - 1]; bd[u - 1] = td;
          int ti = bi[u]; bi[u] = bi[u - 1]; bi[u - 1] = ti;
        }
      }
    }
  }
  #pragma unroll
  for (int u = 0; u < KK; ++u) srcOut[(size_t)q * KK + u] = bi[u];
}

// node matmuls xv/as/ad = h @ {Wlin,Wsrc,Wdst}. R8-exact (wbuf-staged, (4,4)).
__global__ void __launch_bounds__(256)
__attribute__((amdgpu_waves_per_eu(4, 4)))
k_node_mm(const float* __restrict__ hin,
    const float* __restrict__ Wl, const float* __restrict__ Ws, const float* __restrict__ Wd,
    float* __restrict__ xv, float* __restrict__ as_, float* __restrict__ ad_) {
  __shared__ float wbuf[2048];
  __shared__ float vbuf[32 * NMS];
  int t = threadIdx.x;
  size_t nb = (size_t)blockIdx.x * 128;
  int ng = t >> 3, cb = t & 7, c0 = cb * 8;
  const float* Wm[3] = {Wl, Ws, Wd};
  float* Om[3] = {xv, as_, ad_};
  const float4* h4 = (const float4*)hin;
  float acc[3][32];
  #pragma unroll
  for (int m = 0; m < 3; ++m)
    #pragma unroll
    for (int i = 0; i < 32; ++i) acc[m][i] = 0.0f;
  for (int kh = 0; kh < 2; ++kh) {
    #pragma unroll
    for (int r = 0; r < 4; ++r) {
      int flat = r * 256 + t;
      int n = flat >> 3, kq = flat & 7;
      float4 hv = h4[(nb + n) * 16 + kh * 8 + kq];
      vbuf[(kq * 4 + 0) * NMS + n] = hv.x;
      vbuf[(kq * 4 + 1) * NMS + n] = hv.y;
      vbuf[(kq * 4 + 2) * NMS + n] = hv.z;
      vbuf[(kq * 4 + 3) * NMS + n] = hv.w;
    }
    #pragma unroll
    for (int m = 0; m < 3; ++m) {
      {
        const float4* w4 = (const float4*)Wm[m] + kh * 512;
        float4* wb = (float4*)wbuf;
        wb[t] = w4[t];
        wb[256 + t] = w4[256 + t];
      }
      __syncthreads();
      #pragma clang loop unroll_count(2)
      for (int kk = 0; kk < 32; ++kk) {
        float4 v4 = *(const float4*)&vbuf[kk * NMS + 4 * ng];
        float4 w0 = *(const float4*)&wbuf[kk * 64 + c0];
        float4 w1 = *(const float4*)&wbuf[kk * 64 + c0 + 4];
        float vv[4] = {v4.x, v4.y, v4.z, v4.w};
        float wv[8] = {w0.x, w0.y, w0.z, w0.w, w1.x, w1.y, w1.z, w1.w};
        #pragma unroll
        for (int ni = 0; ni < 4; ++ni)
          #pragma unroll
          for (int c = 0; c < 8; ++c)
            acc[m][ni * 8 + c] = fmaf(vv[ni], wv[c], acc[m][ni * 8 + c]);
      }
      __syncthreads();
    }
  }
  #pragma unroll
  for (int m = 0; m < 3; ++m) {
    float* O = Om[m];
    #pragma unroll
    for (int ni = 0; ni < 4; ++ni) {
      *(float4*)(O + (nb + 4 * ng + ni) * 64 + c0) =
          make_float4(acc[m][ni * 8 + 0], acc[m][ni * 8 + 1],
                      acc[m][ni * 8 + 2], acc[m][ni * 8 + 3]);
      *(float4*)(O + (nb + 4 * ng + ni) * 64 + c0 + 4) =
          make_float4(acc[m][ni * 8 + 4], acc[m][ni * 8 + 5],
                      acc[m][ni * 8 + 6], acc[m][ni * 8 + 7]);
    }
  }
}

// Fused edge MLPs + softmax-aggregate. R13 = R8-exact structure (VS=198,
// 3x b64 v-reads, (3,3) pin — proven 300us / 3.1M conflicts / no spill)
// + ONLY the wreg weight prefetch (proven to fit at (3,3): R11 VGPR=80).
// Isolates the prefetch lever from R11's 8-slot layout (which cost +33us).
__global__ void __launch_bounds__(256)
__attribute__((amdgpu_waves_per_eu(3, 3)))
k_edge_fused(
    const float* __restrict__ pos, const int* __restrict__ srcA,
    const float* __restrict__ as_, const float* __restrict__ ad_,
    const float* __restrict__ xv,
    const float* __restrict__ pW1, const float* __restrict__ pB1,
    const float* __restrict__ pW2, const float* __restrict__ pB2,
    const float* __restrict__ aW1, const float* __restrict__ aB1,
    const float* __restrict__ aW2, const float* __restrict__ aB2,
    float* __restrict__ hout) {
  __shared__ float wbuf[2048];        // 8 KB: 32 active W rows
  __shared__ float vbuf[32 * VS];     // 25.3 KB: [k-half-row][edge]
  __shared__ float sbuf[192];         // pW1 | pB1
  __shared__ float pdxs[192], pdys[192];
  __shared__ int   srcb[192];
  int t = threadIdx.x;
  int nb = blockIdx.x * 32;
  int ng = t >> 3;                    // node-in-block 0..31
  int cb = t & 7;
  int cl = 4 * cb;                    // low channel quad (half 0)
  int ch = 32 + 4 * cb;               // high channel quad (half 1)
  int node = nb + ng;

  // ---- prologue (+ initial weight prefetch: stage S0 = pW2 half 0) ----
  float4 wreg0 = ((const float4*)pW2)[t];
  float4 wreg1 = ((const float4*)pW2)[256 + t];
  if (t < 192) {
    int s = srcA[(size_t)nb * KK + t];
    srcb[t] = s;
    int dn = nb + t / KK;
    float2 pd = *(const float2*)(pos + 2 * (size_t)dn);
    float2 ps = *(const float2*)(pos + 2 * (size_t)s);
    pdxs[t] = pd.x - ps.x;
    pdys[t] = pd.y - ps.y;
    sbuf[t] = (t < 128) ? pW1[t] : pB1[t - 128];
  }
  __syncthreads();

  // ---- phase 1: delta = relu(relu(pd@pW1+pB1)@pW2 + pB2) ----
  float d[48];
  {
    float4 b0 = *(const float4*)(pB2 + cl);
    float4 b1 = *(const float4*)(pB2 + ch);
    #pragma unroll
    for (int j = 0; j < 6; ++j) {
      d[j * 8 + 0] = b0.x; d[j * 8 + 1] = b0.y; d[j * 8 + 2] = b0.z; d[j * 8 + 3] = b0.w;
      d[j * 8 + 4] = b1.x; d[j * 8 + 5] = b1.y; d[j * 8 + 6] = b1.z; d[j * 8 + 7] = b1.w;
    }
  }
  #pragma unroll
  for (int h = 0; h < 2; ++h) {
    {
      float4* wb = (float4*)wbuf;
      wb[t] = wreg0;
      wb[256 + t] = wreg1;
    }
    {
      const float4* nxt = (h == 0) ? ((const float4*)pW2 + 512) : ((const float4*)aW1);
      wreg0 = nxt[t];
      wreg1 = nxt[256 + t];
    }
    if (t < 192) {
      float px = pdxs[t], py = pdys[t];
      #pragma clang loop unroll_count(4)
      for (int kk = 0; kk < 32; ++kk) {
        int k = h * 32 + kk;
        float p0 = px * sbuf[k];
        float p1 = py * sbuf[64 + k];
        float ph = fmaxf((p0 + p1) + sbuf[128 + k], 0.0f);
        vbuf[kk * VS + t] = ph;
      }
    }
    __syncthreads();
    #pragma clang loop unroll_count(2)
    for (int kk = 0; kk < 32; ++kk) {
      float2 v01 = *(const float2*)&vbuf[kk * VS + 6 * ng];
      float2 v23 = *(const float2*)&vbuf[kk * VS + 6 * ng + 2];
      float2 v45 = *(const float2*)&vbuf[kk * VS + 6 * ng + 4];
      float4 w0 = *(const float4*)&wbuf[kk * 64 + cl];
      float4 w1 = *(const float4*)&wbuf[kk * 64 + ch];
      float vv[6] = {v01.x, v01.y, v23.x, v23.y, v45.x, v45.y};
      float wv[8] = {w0.x, w0.y, w0.z, w0.w, w1.x, w1.y, w1.z, w1.w};
      #pragma unroll
      for (int j = 0; j < 6; ++j)
        #pragma unroll
        for (int c = 0; c < 8; ++c)
          d[j * 8 + c] = fmaf(vv[j], wv[c], d[j * 8 + c]);
    }
    __syncthreads();
  }
  #pragma unroll
  for (int i = 0; i < 48; ++i) d[i] = fmaxf(d[i], 0.0f);

  // ---- phase 2: r = relu(v @ aW1 + aB1), v = (ad-as)+delta ----
  float r[48];
  {
    float4 b0 = *(const float4*)(aB1 + cl);
    float4 b1 = *(const float4*)(aB1 + ch);
    #pragma unroll
    for (int j = 0; j < 6; ++j) {
      r[j * 8 + 0] = b0.x; r[j * 8 + 1] = b0.y; r[j * 8 + 2] = b0.z; r[j * 8 + 3] = b0.w;
      r[j * 8 + 4] = b1.x; r[j * 8 + 5] = b1.y; r[j * 8 + 6] = b1.z; r[j * 8 + 7] = b1.w;
    }
  }
  #pragma unroll
  for (int h = 0; h < 2; ++h) {
    {
      float4* wb = (float4*)wbuf;
      wb[t] = wreg0;
      wb[256 + t] = wreg1;
    }
    {
      const float4* nxt = (h == 0) ? ((const float4*)aW1 + 512) : ((const float4*)aW2);
      wreg0 = nxt[t];
      wreg1 = nxt[256 + t];
    }
    {
      int cbase = h ? ch : cl;
      float4 av = *(const float4*)(ad_ + (size_t)node * 64 + cbase);
      float vtmp[6][4];
      #pragma unroll
      for (int j = 0; j < 6; ++j) {
        int s = srcb[6 * ng + j];
        float4 sv = *(const float4*)(as_ + (size_t)s * 64 + cbase);
        vtmp[j][0] = (av.x - sv.x) + d[j * 8 + 4 * h + 0];
        vtmp[j][1] = (av.y - sv.y) + d[j * 8 + 4 * h + 1];
        vtmp[j][2] = (av.z - sv.z) + d[j * 8 + 4 * h + 2];
        vtmp[j][3] = (av.w - sv.w) + d[j * 8 + 4 * h + 3];
      }
      #pragma unroll
      for (int cj = 0; cj < 4; ++cj)
        #pragma unroll
        for (int jp = 0; jp < 3; ++jp)
          *(float2*)&vbuf[(4 * cb + cj) * VS + 6 * ng + 2 * jp] =
              make_float2(vtmp[2 * jp][cj], vtmp[2 * jp + 1][cj]);
    }
    __syncthreads();
    #pragma clang loop unroll_count(2)
    for (int kk = 0; kk < 32; ++kk) {
      float2 v01 = *(const float2*)&vbuf[kk * VS + 6 * ng];
      float2 v23 = *(const float2*)&vbuf[kk * VS + 6 * ng + 2];
      float2 v45 = *(const float2*)&vbuf[kk * VS + 6 * ng + 4];
      float4 w0 = *(const float4*)&wbuf[kk * 64 + cl];
      float4 w1 = *(const float4*)&wbuf[kk * 64 + ch];
      float vv[6] = {v01.x, v01.y, v23.x, v23.y, v45.x, v45.y};
      float wv[8] = {w0.x, w0.y, w0.z, w0.w, w1.x, w1.y, w1.z, w1.w};
      #pragma unroll
      for (int j = 0; j < 6; ++j)
        #pragma unroll
        for (int c = 0; c < 8; ++c)
          r[j * 8 + c] = fmaf(vv[j], wv[c], r[j * 8 + c]);
    }
    __syncthreads();
  }
  #pragma unroll
  for (int i = 0; i < 48; ++i) r[i] = fmaxf(r[i], 0.0f);

  // ---- phase 3: a = relu(r @ aW2 + aB2) ----
  float a[48];
  {
    float4 b0 = *(const float4*)(aB2 + cl);
    float4 b1 = *(const float4*)(aB2 + ch);
    #pragma unroll
    for (int j = 0; j < 6; ++j) {
      a[j * 8 + 0] = b0.x; a[j * 8 + 1] = b0.y; a[j * 8 + 2] = b0.z; a[j * 8 + 3] = b0.w;
      a[j * 8 + 4] = b1.x; a[j * 8 + 5] = b1.y; a[j * 8 + 6] = b1.z; a[j * 8 + 7] = b1.w;
    }
  }
  #pragma unroll
  for (int h = 0; h < 2; ++h) {
    {
      float4* wb = (float4*)wbuf;
      wb[t] = wreg0;
      wb[256 + t] = wreg1;
    }
    if (h == 0) {
      const float4* nxt = (const float4*)aW2 + 512;
      wreg0 = nxt[t];
      wreg1 = nxt[256 + t];
    }
    #pragma unroll
    for (int cj = 0; cj < 4; ++cj)
      #pragma unroll
      for (int jp = 0; jp < 3; ++jp)
        *(float2*)&vbuf[(4 * cb + cj) * VS + 6 * ng + 2 * jp] =
            make_float2(r[(2 * jp) * 8 + 4 * h + cj], r[(2 * jp + 1) * 8 + 4 * h + cj]);
    __syncthreads();
    #pragma clang loop unroll_count(2)
    for (int kk = 0; kk < 32; ++kk) {
      float2 v01 = *(const float2*)&vbuf[kk * VS + 6 * ng];
      float2 v23 = *(const float2*)&vbuf[kk * VS + 6 * ng + 2];
      float2 v45 = *(const float2*)&vbuf[kk * VS + 6 * ng + 4];
      float4 w0 = *(const float4*)&wbuf[kk * 64 + cl];
      float4 w1 = *(const float4*)&wbuf[kk * 64 + ch];
      float vv[6] = {v01.x, v01.y, v23.x, v23.y, v45.x, v45.y};
      float wv[8] = {w0.x, w0.y, w0.z, w0.w, w1.x, w1.y, w1.z, w1.w};
      #pragma unroll
      for (int j = 0; j < 6; ++j)
        #pragma unroll
        for (int c = 0; c < 8; ++c)
          a[j * 8 + c] = fmaf(vv[j], wv[c], a[j * 8 + c]);
    }
    __syncthreads();
  }
  #pragma unroll
  for (int i = 0; i < 48; ++i) a[i] = fmaxf(a[i], 0.0f);

  // ---- phase 4: thread-local softmax + max-aggregate (exact reference order) ----
  float m8[8], ss[8], out[8];
  #pragma unroll
  for (int c = 0; c < 8; ++c) m8[c] = a[c];
  #pragma unroll
  for (int j = 1; j < 6; ++j)
    #pragma unroll
    for (int c = 0; c < 8; ++c) m8[c] = fmaxf(m8[c], a[j * 8 + c]);
  #pragma unroll
  for (int c = 0; c < 8; ++c) ss[c] = 0.0f;
  #pragma unroll
  for (int j = 0; j < 6; ++j)
    #pragma unroll
    for (int c = 0; c < 8; ++c) ss[c] += expf(a[j * 8 + c] - m8[c]);
  #pragma unroll
  for (int j = 0; j < 6; ++j) {
    int s = srcb[6 * ng + j];
    float4 x0 = *(const float4*)(xv + (size_t)s * 64 + cl);
    float4 x1 = *(const float4*)(xv + (size_t)s * 64 + ch);
    float xa[8] = {x0.x, x0.y, x0.z, x0.w, x1.x, x1.y, x1.z, x1.w};
    #pragma unroll
    for (int c = 0; c < 8; ++c) {
      float ej = expf(a[j * 8 + c] - m8[c]);
      float alpha = ej / ss[c];
      float val = alpha * (xa[c] + d[j * 8 + c]);
      out[c] = (j == 0) ? val : fmaxf(out[c], val);
    }
  }
  *(float4*)(hout + (size_t)node * 64 + cl) = make_float4(out[0], out[1], out[2], out[3]);
  *(float4*)(hout + (size_t)node * 64 + ch) = make_float4(out[4], out[5], out[6], out[7]);
}

__global__ void k_head(const float* __restrict__ g, const float* __restrict__ hw,
                       const float* __restrict__ hb, float* __restrict__ out) {
  int t = threadIdx.x;
  if (t >= BG * 2) return;
  int b = t >> 1, o = t & 1;
  float acc = 0.0f;
  for (int k = 0; k < D; ++k) acc = fmaf(g[b * D + k], hw[k * 2 + o], acc);
  out[b * 2 + o] = acc + hb[o];
}

extern "C" void kernel_launch(void* const* d_in, const int* in_sizes, int n_in,
                              void* d_out, int out_size, void* d_ws, size_t ws_size,
                              hipStream_t stream) {
  (void)in_sizes; (void)n_in; (void)out_size; (void)ws_size;
  const float* x      = (const float*)d_in[0];
  const float* pos_c  = (const float*)d_in[1];
  const int*   src_c  = (const int*)d_in[2];
  const int*   batch  = (const int*)d_in[4];
  const int*   sc_id0 = (const int*)d_in[5];
  const float* pos_s0 = (const float*)d_in[6];
  const int*   sc_id1 = (const int*)d_in[7];
  const float* pos_s1 = (const float*)d_in[8];
  const float* Wlin = (const float*)d_in[9];
  const float* Wsrc = (const float*)d_in[10];
  const float* Wdst = (const float*)d_in[11];
  const float* pW1  = (const float*)d_in[12];
  const float* pB1  = (const float*)d_in[13];
  const float* pW2  = (const float*)d_in[14];
  const float* pB2  = (const float*)d_in[15];
  const float* aW1  = (const float*)d_in[16];
  const float* aB1  = (const float*)d_in[17];
  const float* aW2  = (const float*)d_in[18];
  const float* aB2  = (const float*)d_in[19];
  const float* hw   = (const float*)d_in[20];
  const float* hb   = (const float*)d_in[21];
  float* outp = (float*)d_out;

  char* ws = (char*)d_ws;
  size_t off = 0;
  auto alloc = [&](size_t bytes) -> void* {
    void* p = ws + off; off = (off + bytes + 255) & ~(size_t)255; return p;
  };
  float* h   = (float*)alloc((size_t)NN * D * 4);
  float* xv  = (float*)alloc((size_t)NN * D * 4);
  float* as_ = (float*)alloc((size_t)NN * D * 4);
  float* ad_ = (float*)alloc((size_t)NN * D * 4);
  float* h0  = (float*)alloc((size_t)C0N * D * 4);
  float* h1  = (float*)alloc((size_t)C1N * D * 4);
  float* g   = (float*)alloc((size_t)BG * D * 4);
  int* cl0   = (int*)alloc((size_t)NN * 4);
  int* cl1   = (int*)alloc((size_t)C0N * 4);
  int* b0    = (int*)alloc((size_t)C0N * 4);
  int* b1    = (int*)alloc((size_t)C1N * 4);
  int* src0  = (int*)alloc((size_t)C0N * KK * 4);
  int* src1  = (int*)alloc((size_t)C1N * KK * 4);
  float* kd  = (float*)alloc((size_t)C0N * SEG0 * KK * 4);
  int*   ki  = (int*)alloc((size_t)C0N * SEG0 * KK * 4);
  int* mx    = (int*)alloc(256);
  int* offb  = (int*)alloc(256);

  auto ptconv = [&](int n, const float* pos, const int* srcA,
                    const float* hin, float* hout, int l) {
    k_node_mm<<<n / 128, 256, 0, stream>>>(hin,
        Wlin + (size_t)l * 4096, Wsrc + (size_t)l * 4096, Wdst + (size_t)l * 4096,
        xv, as_, ad_);
    k_edge_fused<<<n / 32, 256, 0, stream>>>(pos, srcA, as_, ad_, xv,
        pW1 + (size_t)l * 128, pB1 + (size_t)l * 64,
        pW2 + (size_t)l * 4096, pB2 + (size_t)l * 64,
        aW1 + (size_t)l * 4096, aB1 + (size_t)l * 64,
        aW2 + (size_t)l * 4096, aB2 + (size_t)l * 64,
        hout);
  };

  // ---- structure precompute (gen_cluster, batches, knn graphs) ----
  k_init_u32<<<1, 64, 0, stream>>>((unsigned*)mx, 0x80000000u, BG);
  k_seg_max_small<BG><<<64, 256, 0, stream>>>(sc_id0, batch, mx, NN);
  k_cumsum_off<<<1, 1, 0, stream>>>(mx, offb, BG);
  k_gen_cl<<<NN / 256, 256, 0, stream>>>(sc_id0, batch, offb, cl0, NN);
  k_init_u32<<<(C0N + 255) / 256, 256, 0, stream>>>((unsigned*)b0, 0x80000000u, C0N);
  k_seg_max_i32<<<NN / 256, 256, 0, stream>>>(batch, cl0, b0, NN);
  k_knn_part<<<(C0N / 256) * SEG0, 256, 0, stream>>>(pos_s0, C0PG, SEG0, kd, ki);
  k_knn_merge<<<C0N / 256, 256, 0, stream>>>(kd, ki, SEG0, src0, C0N);
  k_init_u32<<<1, 64, 0, stream>>>((unsigned*)mx, 0x80000000u, BG);
  k_seg_max_small<BG><<<64, 256, 0, stream>>>(sc_id1, b0, mx, C0N);
  k_cumsum_off<<<1, 1, 0, stream>>>(mx, offb, BG);
  k_gen_cl<<<C0N / 256, 256, 0, stream>>>(sc_id1, b0, offb, cl1, C0N);
  k_init_u32<<<(C1N + 255) / 256, 256, 0, stream>>>((unsigned*)b1, 0x80000000u, C1N);
  k_seg_max_i32<<<C0N / 256, 256, 0, stream>>>(b0, cl1, b1, C0N);
  k_knn<<<C1N / 256, 256, 0, stream>>>(pos_s1, C1PG, src1);

  // ---- cluster level (4 layers) ----
  ptconv(NN, pos_c, src_c, x, h, 0);
  for (int l = 1; l < 4; ++l) ptconv(NN, pos_c, src_c, h, h, l);
  // pool -> h0
  k_init_u32<<<C0N * D / 256, 256, 0, stream>>>((unsigned*)h0, 0x007fffffu, C0N * D);
  k_pool_f32<<<NN * D / 256, 256, 0, stream>>>(h, cl0, (unsigned*)h0, NN * D);
  k_decode_f32<<<C0N * D / 256, 256, 0, stream>>>((unsigned*)h0, C0N * D);
  // ---- SC0 level (3 layers) ----
  for (int l = 4; l < 7; ++l) ptconv(C0N, pos_s0, src0, h0, h0, l);
  // pool -> h1
  k_init_u32<<<C1N * D / 256, 256, 0, stream>>>((unsigned*)h1, 0x007fffffu, C1N * D);
  k_pool_f32<<<C0N * D / 256, 256, 0, stream>>>(h0, cl1, (unsigned*)h1, C0N * D);
  k_decode_f32<<<C1N * D / 256, 256, 0, stream>>>((unsigned*)h1, C1N * D);
  // ---- SC1 level (3 layers) ----
  for (int l = 7; l < 10; ++l) ptconv(C1N, pos_s1, src1, h1, h1, l);
  // ---- global max pool + head ----
  k_init_u32<<<(BG * D + 255) / 256, 256, 0, stream>>>((unsigned*)g, 0x007fffffu, BG * D);
  k_pool_f32<<<C1N * D / 256, 256, 0, stream>>>(h1, b1, (unsigned*)g, C1N * D);
  k_decode_f32<<<(BG * D + 255) / 256, 256, 0, stream>>>((unsigned*)g, BG * D);
  k_head<<<1, 64, 0, stream>>>(g, hw, hb, outp);
}